// Round 2
// baseline (31391.873 us; speedup 1.0000x reference)
//
#include <hip/hip_runtime.h>
#include <hip/hip_bf16.h>

#define NBLK 128
#define NTHR 256
#define HH   1024
#define BB   64
#define TT   1024
#define SS   8                 // hidden units per block
#define COLS 32                // 4 gates * SS
#define PITCH 1032             // LDS weight pitch (shorts): pad breaks conflicts, keeps 16B align
#define WELEMS (COLS * PITCH)
#define ZPITCH 33
#define SMEM_BYTES (WELEMS * 2 + 2 * 64 * ZPITCH * 4 + 3 * 32 * 4)  // 83328

typedef __bf16 bf16x8 __attribute__((ext_vector_type(8)));
typedef float  f32x4  __attribute__((ext_vector_type(4)));

__device__ __forceinline__ unsigned short f2bf(float x) {
  unsigned int u = __builtin_bit_cast(unsigned int, x);
  u = (u + 0x7fffu + ((u >> 16) & 1u)) >> 16;   // RNE
  return (unsigned short)u;
}
__device__ __forceinline__ float sigm(float x)  { return 1.f / (1.f + __expf(-x)); }
__device__ __forceinline__ float tanhx(float x) { return 2.f / (1.f + __expf(-2.f * x)) - 1.f; }

// Gather one (1024 x 32) column-slice of a (1024 x 4096) fp32 weight into LDS as bf16.
__device__ __forceinline__ void gather_w(const float* __restrict__ Wg, int colbase,
                                         unsigned short* dst) {
  const int tid = threadIdx.x;
  const int n   = tid & 31;
  const int kg  = tid >> 5;  // 0..7
  const int col = (n >> 3) * HH + colbase + (n & 7);
#pragma unroll 8
  for (int kk = 0; kk < 128; ++kk) {
    const int k = kg * 128 + kk;
    dst[n * PITCH + k] = f2bf(Wg[(size_t)k * 4096 + col]);
  }
}

// ---- Data-flow sync: per-producer monotonic progress counters ----
// prog[b] (one int per block, own 128B line) is store-RELEASED to p+1 by block b's
// tid 0 after the end-of-step __syncthreads (which drains the step's vmem stores).
// Consumer wave wv reads h-prev K in [wv*256, wv*256+256) -> produced by exactly
// blocks 32wv..32wv+31: lane l polls prog[32wv + (l&31)] until __all(v >= p), then
// acquire-fences. Owner-only WRITES (no RMW contention); pollers only read.
// Happens-before chain: block publishing step p-1 has observed ALL 128 prog >= p-1
// (its 4 waves jointly cover all producers before the reduce barrier) => every block
// published p-2 => all step-(p-2) loads drained (vmcnt(0) precedes each publish).
// This carries both WAR hazards: h double-buffer reuse and the stash upper-half
// overwrite by the delayed fp32 h2 write.
__device__ __forceinline__ void wait_step(int* prog, int p, int wv, int lane) {
  int* a = prog + (((wv << 5) + (lane & 31)) << 5);   // stride 32 ints = 128B/line
  for (;;) {
    const int v = __hip_atomic_load(a, __ATOMIC_RELAXED, __HIP_MEMORY_SCOPE_AGENT);
    if (__all(v >= p)) break;
    __builtin_amdgcn_s_sleep(1);
  }
  __builtin_amdgcn_fence(__ATOMIC_ACQUIRE, "agent");
}

__global__ void __launch_bounds__(NTHR, 1) lstm_persist(
    const float* __restrict__ x,   const float* __restrict__ Wi0,
    const float* __restrict__ Wh0, const float* __restrict__ b0,
    const float* __restrict__ Wi1, const float* __restrict__ Wh1,
    const float* __restrict__ b1,  float* out,
    int* prog, unsigned short* hbuf) {
  extern __shared__ unsigned short smem_us[];
  unsigned short* w0 = smem_us;                 // transient weight staging
  float* zbuf = (float*)(smem_us + WELEMS);     // [2][64][ZPITCH]
  float* wi0s = zbuf + 2 * 64 * ZPITCH;
  float* b0s  = wi0s + 32;
  float* b1s  = b0s + 32;

  const int tid     = threadIdx.x;
  const int lane    = tid & 63;
  const int wv      = tid >> 6;
  const int colbase = blockIdx.x * SS;

  if (tid < 32) {
    const int col = (tid >> 3) * HH + colbase + (tid & 7);
    wi0s[tid] = Wi0[col];
    b0s[tid]  = b0[col];
    b1s[tid]  = b1[col];
  }

  const int kq = wv * 256;
  const int lm = lane & 15;
  const int lk = (lane >> 4) * 8;
  const f32x4 fzero = {0.f, 0.f, 0.f, 0.f};

  // ---- register-resident B fragments (loop-invariant weights) ----
  bf16x8 bW0[16];   // phase A: Wh0; phase B: Wi1   [kc*2+nt]
  bf16x8 bW1[16];   // phase B: Wh1
  gather_w(Wh0, colbase, w0);
  __syncthreads();
#pragma unroll
  for (int kc = 0; kc < 8; ++kc)
#pragma unroll
    for (int nt = 0; nt < 2; ++nt)
      bW0[kc * 2 + nt] =
          *reinterpret_cast<const bf16x8*>(w0 + (nt * 16 + lm) * PITCH + kq + kc * 32 + lk);

  // pointwise ownership: thread -> (sample ps, hidden pair pj, pj+1)
  const int ps = tid >> 2;
  const int pj = (tid & 3) * 2;
  float c_a = 0.f, c_b = 0.f;
  float hp2a = 0.f, hp2b = 0.f;
  float hl_a = 0.f, hl_b = 0.f;

  float* h2out = out + 2 * BB * HH;
  unsigned short* stash = (unsigned short*)h2out;  // bf16 h1-history in upper-half fp32 slots

  bf16x8 pf[32];   // phase B: prefetched Wi1 A-operand (stash[t]) [kc*4+mt]

  for (int p = 0; p < 2048; ++p) {
    const bool phB = (p >= 1024);
    const int  t   = phB ? (p - 1024) : p;
    const unsigned short* hprev = hbuf + ((p + 1) & 1) * (BB * HH);

    if (p == 1024) {  // phase switch (uniform): stage layer-1 weights into registers
      __syncthreads();
      gather_w(Wi1, colbase, w0);
      __syncthreads();
#pragma unroll
      for (int kc = 0; kc < 8; ++kc)
#pragma unroll
        for (int nt = 0; nt < 2; ++nt)
          bW0[kc * 2 + nt] =
              *reinterpret_cast<const bf16x8*>(w0 + (nt * 16 + lm) * PITCH + kq + kc * 32 + lk);
      __syncthreads();
      gather_w(Wh1, colbase, w0);
      __syncthreads();
#pragma unroll
      for (int kc = 0; kc < 8; ++kc)
#pragma unroll
        for (int nt = 0; nt < 2; ++nt)
          bW1[kc * 2 + nt] =
              *reinterpret_cast<const bf16x8*>(w0 + (nt * 16 + lm) * PITCH + kq + kc * 32 + lk);
      // prefetch stash[0] (written at p=0; every block is past step 1023 => long drained)
      const unsigned short* sb = stash + 1024;
#pragma unroll
      for (int kc = 0; kc < 8; ++kc) {
        const int k0 = kq + kc * 32 + lk;
#pragma unroll
        for (int mt = 0; mt < 4; ++mt)
          pf[kc * 4 + mt] =
              *reinterpret_cast<const bf16x8*>(sb + (size_t)(mt * 16 + lm) * 2097152 + k0);
      }
    }

    f32x4 acc[4][2];
#pragma unroll
    for (int i = 0; i < 4; ++i)
#pragma unroll
      for (int j = 0; j < 2; ++j) acc[i][j] = fzero;

    float xs = 0.f;

    if (!phB) {
      // preload x pre-poll (constant input -> safe; hides one LLC latency)
      xs = x[(size_t)ps * TT + t];
      if (p > 0) wait_step(prog, p, wv, lane);
      // ---- phase A: h_prev @ Wh0 (A from global, B from registers) ----
#pragma unroll
      for (int kc = 0; kc < 8; ++kc) {
        const int k0 = kq + kc * 32 + lk;
        bf16x8 af[4];
#pragma unroll
        for (int mt = 0; mt < 4; ++mt)
          af[mt] = *reinterpret_cast<const bf16x8*>(hprev + (size_t)(mt * 16 + lm) * HH + k0);
#pragma unroll
        for (int nt = 0; nt < 2; ++nt)
#pragma unroll
          for (int mt = 0; mt < 4; ++mt)
            acc[mt][nt] =
                __builtin_amdgcn_mfma_f32_16x16x32_bf16(af[mt], bW0[kc * 2 + nt], acc[mt][nt], 0, 0, 0);
      }
    } else {
      // ---- phase B matmul 1: h1_hist[t] @ Wi1 — register-only, overlaps the poll ----
#pragma unroll
      for (int kc = 0; kc < 8; ++kc)
#pragma unroll
        for (int nt = 0; nt < 2; ++nt)
#pragma unroll
          for (int mt = 0; mt < 4; ++mt)
            acc[mt][nt] =
                __builtin_amdgcn_mfma_f32_16x16x32_bf16(pf[kc * 4 + mt], bW0[kc * 2 + nt],
                                                        acc[mt][nt], 0, 0, 0);
      wait_step(prog, p, wv, lane);
      // delayed fp32 h2 write for t-1: MUST be post-poll. prog>=p observed =>
      // those producers published p-1 => all 128 published p-2 => every block's
      // prefetch of stash[t-1] (issued at its step p-2) drained => WAR-safe.
      if (t > 0) {
        float* o = h2out + (size_t)ps * (TT * HH) + (size_t)(t - 1) * HH + colbase + pj;
        o[0] = hp2a; o[1] = hp2b;
      }
      // ---- phase B matmul 2: h_prev @ Wh1 ----
#pragma unroll
      for (int kc = 0; kc < 8; ++kc) {
        const int k0 = kq + kc * 32 + lk;
        bf16x8 af[4];
#pragma unroll
        for (int mt = 0; mt < 4; ++mt)
          af[mt] = *reinterpret_cast<const bf16x8*>(hprev + (size_t)(mt * 16 + lm) * HH + k0);
#pragma unroll
        for (int nt = 0; nt < 2; ++nt)
#pragma unroll
          for (int mt = 0; mt < 4; ++mt)
            acc[mt][nt] =
                __builtin_amdgcn_mfma_f32_16x16x32_bf16(af[mt], bW1[kc * 2 + nt], acc[mt][nt], 0, 0, 0);
      }
      // ---- prefetch stash[t+1] for next period (consumed next step; latency fully hidden) ----
      if (t < 1023) {
        const unsigned short* sb = stash + (size_t)(t + 1) * 2048 + 1024;
#pragma unroll
        for (int kc = 0; kc < 8; ++kc) {
          const int k0 = kq + kc * 32 + lk;
#pragma unroll
          for (int mt = 0; mt < 4; ++mt)
            pf[kc * 4 + mt] =
                *reinterpret_cast<const bf16x8*>(sb + (size_t)(mt * 16 + lm) * 2097152 + k0);
        }
      }
    }

    // ---- K-partial reduction through LDS: buf0 = wv0+wv2, buf1 = wv1+wv3 ----
    if (wv >= 2) {
      float* zb = zbuf + (size_t)(wv - 2) * (64 * ZPITCH);
#pragma unroll
      for (int mt = 0; mt < 4; ++mt)
#pragma unroll
        for (int nt = 0; nt < 2; ++nt)
#pragma unroll
          for (int q = 0; q < 4; ++q)
            zb[(mt * 16 + (lane >> 4) * 4 + q) * ZPITCH + nt * 16 + lm] = acc[mt][nt][q];
    }
    __syncthreads();
    if (wv < 2) {
      float* zb = zbuf + (size_t)wv * (64 * ZPITCH);
#pragma unroll
      for (int mt = 0; mt < 4; ++mt)
#pragma unroll
        for (int nt = 0; nt < 2; ++nt)
#pragma unroll
          for (int q = 0; q < 4; ++q)
            zb[(mt * 16 + (lane >> 4) * 4 + q) * ZPITCH + nt * 16 + lm] += acc[mt][nt][q];
    }
    __syncthreads();

    // ---- pointwise gates + cell update (2 hidden units / thread) ----
    {
      float hh2[2];
      float cc[2] = {c_a, c_b};
#pragma unroll
      for (int u = 0; u < 2; ++u) {
        const int jn = pj + u;
        float zg[4];
#pragma unroll
        for (int g4 = 0; g4 < 4; ++g4) {
          const int n = g4 * 8 + jn;
          float z = zbuf[ps * ZPITCH + n] + zbuf[64 * ZPITCH + ps * ZPITCH + n];
          z += phB ? b1s[n] : (xs * wi0s[n] + b0s[n]);
          zg[g4] = z;
        }
        const float gi = sigm(zg[0]);
        const float gf = sigm(zg[1]);
        const float gg = tanhx(zg[2]);
        const float go = sigm(zg[3]);
        const float c  = gf * cc[u] + gi * gg;
        cc[u]  = c;
        hh2[u] = go * tanhx(c);
      }
      c_a = cc[0]; c_b = cc[1];
      const unsigned int packed =
          (unsigned int)f2bf(hh2[0]) | ((unsigned int)f2bf(hh2[1]) << 16);
      *(unsigned int*)(hbuf + (p & 1) * (BB * HH) + ps * HH + colbase + pj) = packed;
      if (!phB) {
        *(unsigned int*)(stash + (size_t)ps * 2097152 + (size_t)t * 2048 + 1024 + colbase + pj) = packed;
      } else {
        hp2a = hh2[0]; hp2b = hh2[1];
        if (t == 1023) { hl_a = hh2[0]; hl_b = hh2[1]; }
      }
    }

    // ---- publish: drain stores (vmcnt(0) at barrier), then owner-only release store ----
    __syncthreads();
    if (tid == 0)
      __hip_atomic_store(&prog[blockIdx.x << 5], p + 1, __ATOMIC_RELEASE,
                         __HIP_MEMORY_SCOPE_AGENT);
  }

  // epilogue: flush h2[1023], final c1 and h1 (all own data; any other block's
  // prefetch of stash[1023] drained before it published step 2046)
  {
    float* o = h2out + (size_t)ps * (TT * HH) + (size_t)1023 * HH + colbase + pj;
    o[0] = hp2a; o[1] = hp2b;
    out[ps * HH + colbase + pj]     = c_a;
    out[ps * HH + colbase + pj + 1] = c_b;
    float* ho = out + BB * HH;
    ho[ps * HH + colbase + pj]     = hl_a;
    ho[ps * HH + colbase + pj + 1] = hl_b;
  }
}

extern "C" void kernel_launch(void* const* d_in, const int* in_sizes, int n_in,
                              void* d_out, int out_size, void* d_ws, size_t ws_size,
                              hipStream_t stream) {
  const float* x   = (const float*)d_in[0];
  const float* Wi0 = (const float*)d_in[1];
  const float* Wh0 = (const float*)d_in[2];
  const float* b0  = (const float*)d_in[3];
  const float* Wi1 = (const float*)d_in[4];
  const float* Wh1 = (const float*)d_in[5];
  const float* b1  = (const float*)d_in[6];

  // ws layout: [0, 16K) progress counters (128 blocks x 128B line),
  //            [16K, 16K+256K) h double-buffer (2 x 64 x 1024 bf16)
  // total 278528 B -- inside the previously-proven 344064 B footprint.
  int* prog = (int*)d_ws;
  unsigned short* hbuf = (unsigned short*)((char*)d_ws + 16384);

  (void)hipMemsetAsync(d_ws, 0, 16384 + 2 * BB * HH * 2, stream);

  (void)hipFuncSetAttribute((const void*)lstm_persist,
                            hipFuncAttributeMaxDynamicSharedMemorySize, SMEM_BYTES);

  lstm_persist<<<dim3(NBLK), dim3(NTHR), SMEM_BYTES, stream>>>(
      x, Wi0, Wh0, b0, Wi1, Wh1, b1, (float*)d_out, prog, hbuf);
}

// Round 3
// 30071.017 us; speedup vs baseline: 1.0439x; 1.0439x over previous
//
#include <hip/hip_runtime.h>
#include <hip/hip_bf16.h>

#define NBLK 128
#define NTHR 256
#define HH   1024
#define BB   64
#define TT   1024
#define SS   8                 // hidden units per block
#define COLS 32                // 4 gates * SS
#define PITCH 1032             // LDS weight pitch (shorts): pad breaks conflicts, keeps 16B align
#define WELEMS (COLS * PITCH)
#define ZPITCH 33
#define SMEM_BYTES (WELEMS * 2 + 2 * 64 * ZPITCH * 4 + 3 * 32 * 4)  // 83328

typedef __bf16 bf16x8 __attribute__((ext_vector_type(8)));
typedef float  f32x4  __attribute__((ext_vector_type(4)));

__device__ __forceinline__ unsigned short f2bf(float x) {
  unsigned int u = __builtin_bit_cast(unsigned int, x);
  u = (u + 0x7fffu + ((u >> 16) & 1u)) >> 16;   // RNE
  return (unsigned short)u;
}
__device__ __forceinline__ float sigm(float x)  { return 1.f / (1.f + __expf(-x)); }
__device__ __forceinline__ float tanhx(float x) { return 2.f / (1.f + __expf(-2.f * x)) - 1.f; }

// LLC-direct accessors: agent-scope RELAXED atomics compile to sc0/sc1 loads/stores
// that read/write through to the Infinity Cache. Because ALL cross-block data moves
// through these, no release/acquire fence (buffer_wbl2 / buffer_inv) is needed
// anywhere: __syncthreads' vmcnt(0) proves stores reached the LLC before the arrival
// store issues, and the LLC is the single coherence point.
__device__ __forceinline__ bf16x8 llc_load16(const unsigned short* ptr) {
  struct alignas(16) Q { unsigned long long a, b; } q;
  unsigned long long* pp = (unsigned long long*)ptr;
  q.a = __hip_atomic_load(pp,     __ATOMIC_RELAXED, __HIP_MEMORY_SCOPE_AGENT);
  q.b = __hip_atomic_load(pp + 1, __ATOMIC_RELAXED, __HIP_MEMORY_SCOPE_AGENT);
  return __builtin_bit_cast(bf16x8, q);
}
__device__ __forceinline__ void llc_store4(unsigned short* ptr, unsigned int v) {
  __hip_atomic_store((unsigned int*)ptr, v, __ATOMIC_RELAXED, __HIP_MEMORY_SCOPE_AGENT);
}

// Gather one (1024 x 32) column-slice of a (1024 x 4096) fp32 weight into LDS as bf16.
__device__ __forceinline__ void gather_w(const float* __restrict__ Wg, int colbase,
                                         unsigned short* dst) {
  const int tid = threadIdx.x;
  const int n   = tid & 31;
  const int kg  = tid >> 5;  // 0..7
  const int col = (n >> 3) * HH + colbase + (n & 7);
#pragma unroll 8
  for (int kk = 0; kk < 128; ++kk) {
    const int k = kg * 128 + kk;
    dst[n * PITCH + k] = f2bf(Wg[(size_t)k * 4096 + col]);
  }
}

// Wait for step pm1's flag. Single reader thread on a single read-only line,
// then block-wide broadcast via syncthreads (also the compiler/memory barrier
// that keeps subsequent LLC loads from hoisting above the wait).
__device__ __forceinline__ void wait_flag(int* flag, int pm1) {
  if (threadIdx.x == 0) {
    while (__hip_atomic_load(&flag[pm1 << 2], __ATOMIC_RELAXED,
                             __HIP_MEMORY_SCOPE_AGENT) == 0)
      __builtin_amdgcn_s_sleep(1);
  }
  __syncthreads();
}

__global__ void __launch_bounds__(NTHR, 1) lstm_persist(
    const float* __restrict__ x,   const float* __restrict__ Wi0,
    const float* __restrict__ Wh0, const float* __restrict__ b0,
    const float* __restrict__ Wi1, const float* __restrict__ Wh1,
    const float* __restrict__ b1,  float* out,
    int* prog, int* flag, unsigned short* hbuf) {
  extern __shared__ unsigned short smem_us[];
  unsigned short* w0 = smem_us;                 // transient weight staging
  float* zbuf = (float*)(smem_us + WELEMS);     // [2][64][ZPITCH]
  float* wi0s = zbuf + 2 * 64 * ZPITCH;
  float* b0s  = wi0s + 32;
  float* b1s  = b0s + 32;

  const int tid     = threadIdx.x;
  const int lane    = tid & 63;
  const int wv      = tid >> 6;
  const int colbase = blockIdx.x * SS;

  if (tid < 32) {
    const int col = (tid >> 3) * HH + colbase + (tid & 7);
    wi0s[tid] = Wi0[col];
    b0s[tid]  = b0[col];
    b1s[tid]  = b1[col];
  }

  const int kq = wv * 256;
  const int lm = lane & 15;
  const int lk = (lane >> 4) * 8;
  const f32x4 fzero = {0.f, 0.f, 0.f, 0.f};

  // ---- register-resident B fragments (loop-invariant weights) ----
  bf16x8 bW0[16];   // phase A: Wh0; phase B: Wi1   [kc*2+nt]
  bf16x8 bW1[16];   // phase B: Wh1
  gather_w(Wh0, colbase, w0);
  __syncthreads();
#pragma unroll
  for (int kc = 0; kc < 8; ++kc)
#pragma unroll
    for (int nt = 0; nt < 2; ++nt)
      bW0[kc * 2 + nt] =
          *reinterpret_cast<const bf16x8*>(w0 + (nt * 16 + lm) * PITCH + kq + kc * 32 + lk);

  // pointwise ownership: thread -> (sample ps, hidden pair pj, pj+1)
  const int ps = tid >> 2;
  const int pj = (tid & 3) * 2;
  float c_a = 0.f, c_b = 0.f;
  float hp2a = 0.f, hp2b = 0.f;
  float hl_a = 0.f, hl_b = 0.f;

  float* h2out = out + 2 * BB * HH;
  unsigned short* stash = (unsigned short*)h2out;  // bf16 h1-history in upper-half fp32 slots

  bf16x8 pf[32];   // phase B: prefetched Wi1 A-operand (stash[t]) [kc*4+mt]

  for (int p = 0; p < 2048; ++p) {
    const bool phB = (p >= 1024);
    const int  t   = phB ? (p - 1024) : p;
    const unsigned short* hprev = hbuf + ((p + 1) & 1) * (BB * HH);

    if (p == 1024) {  // phase switch (uniform): stage layer-1 weights into registers
      __syncthreads();
      gather_w(Wi1, colbase, w0);
      __syncthreads();
#pragma unroll
      for (int kc = 0; kc < 8; ++kc)
#pragma unroll
        for (int nt = 0; nt < 2; ++nt)
          bW0[kc * 2 + nt] =
              *reinterpret_cast<const bf16x8*>(w0 + (nt * 16 + lm) * PITCH + kq + kc * 32 + lk);
      __syncthreads();
      gather_w(Wh1, colbase, w0);
      __syncthreads();
#pragma unroll
      for (int kc = 0; kc < 8; ++kc)
#pragma unroll
        for (int nt = 0; nt < 2; ++nt)
          bW1[kc * 2 + nt] =
              *reinterpret_cast<const bf16x8*>(w0 + (nt * 16 + lm) * PITCH + kq + kc * 32 + lk);
      // prefetch stash[0] (written at p=0; we passed flag[1022] => at LLC long ago)
      const unsigned short* sb = stash + 1024;
#pragma unroll
      for (int kc = 0; kc < 8; ++kc) {
        const int k0 = kq + kc * 32 + lk;
#pragma unroll
        for (int mt = 0; mt < 4; ++mt)
          pf[kc * 4 + mt] = llc_load16(sb + (size_t)(mt * 16 + lm) * 2097152 + k0);
      }
    }

    f32x4 acc[4][2];
#pragma unroll
    for (int i = 0; i < 4; ++i)
#pragma unroll
      for (int j = 0; j < 2; ++j) acc[i][j] = fzero;

    float xs = 0.f;

    if (!phB) {
      // preload x pre-wait (read-only; stays L2-resident now that nothing invalidates L2)
      xs = x[(size_t)ps * TT + t];
      if (p > 0) wait_flag(flag, p - 1);
      // ---- phase A: h_prev @ Wh0 (A via LLC-direct loads, B from registers) ----
#pragma unroll
      for (int kc = 0; kc < 8; ++kc) {
        const int k0 = kq + kc * 32 + lk;
        bf16x8 af[4];
#pragma unroll
        for (int mt = 0; mt < 4; ++mt)
          af[mt] = llc_load16(hprev + (size_t)(mt * 16 + lm) * HH + k0);
#pragma unroll
        for (int nt = 0; nt < 2; ++nt)
#pragma unroll
          for (int mt = 0; mt < 4; ++mt)
            acc[mt][nt] =
                __builtin_amdgcn_mfma_f32_16x16x32_bf16(af[mt], bW0[kc * 2 + nt], acc[mt][nt], 0, 0, 0);
      }
    } else {
      // ---- phase B matmul 1: h1_hist[t] @ Wi1 — register-only, overlaps the wait ----
#pragma unroll
      for (int kc = 0; kc < 8; ++kc)
#pragma unroll
        for (int nt = 0; nt < 2; ++nt)
#pragma unroll
          for (int mt = 0; mt < 4; ++mt)
            acc[mt][nt] =
                __builtin_amdgcn_mfma_f32_16x16x32_bf16(pf[kc * 4 + mt], bW0[kc * 2 + nt],
                                                        acc[mt][nt], 0, 0, 0);
      wait_flag(flag, p - 1);
      // delayed fp32 h2 write for t-1: post-wait. flag[p-1] => all arrived p-1 =>
      // flag[p-2] was seen by all => step-(p-2) loads (incl. every block's prefetch
      // of stash[t-1]) drained => clobbering stash[t-1]'s bytes is WAR-safe.
      if (t > 0) {
        float* o = h2out + (size_t)ps * (TT * HH) + (size_t)(t - 1) * HH + colbase + pj;
        o[0] = hp2a; o[1] = hp2b;
      }
      // ---- phase B matmul 2: h_prev @ Wh1 ----
#pragma unroll
      for (int kc = 0; kc < 8; ++kc) {
        const int k0 = kq + kc * 32 + lk;
        bf16x8 af[4];
#pragma unroll
        for (int mt = 0; mt < 4; ++mt)
          af[mt] = llc_load16(hprev + (size_t)(mt * 16 + lm) * HH + k0);
#pragma unroll
        for (int nt = 0; nt < 2; ++nt)
#pragma unroll
          for (int mt = 0; mt < 4; ++mt)
            acc[mt][nt] =
                __builtin_amdgcn_mfma_f32_16x16x32_bf16(af[mt], bW1[kc * 2 + nt], acc[mt][nt], 0, 0, 0);
      }
      // ---- prefetch stash[t+1] for next period ----
      if (t < 1023) {
        const unsigned short* sb = stash + (size_t)(t + 1) * 2048 + 1024;
#pragma unroll
        for (int kc = 0; kc < 8; ++kc) {
          const int k0 = kq + kc * 32 + lk;
#pragma unroll
          for (int mt = 0; mt < 4; ++mt)
            pf[kc * 4 + mt] = llc_load16(sb + (size_t)(mt * 16 + lm) * 2097152 + k0);
        }
      }
    }

    // ---- K-partial reduction through LDS: buf0 = wv0+wv2, buf1 = wv1+wv3 ----
    if (wv >= 2) {
      float* zb = zbuf + (size_t)(wv - 2) * (64 * ZPITCH);
#pragma unroll
      for (int mt = 0; mt < 4; ++mt)
#pragma unroll
        for (int nt = 0; nt < 2; ++nt)
#pragma unroll
          for (int q = 0; q < 4; ++q)
            zb[(mt * 16 + (lane >> 4) * 4 + q) * ZPITCH + nt * 16 + lm] = acc[mt][nt][q];
    }
    __syncthreads();
    if (wv < 2) {
      float* zb = zbuf + (size_t)wv * (64 * ZPITCH);
#pragma unroll
      for (int mt = 0; mt < 4; ++mt)
#pragma unroll
        for (int nt = 0; nt < 2; ++nt)
#pragma unroll
          for (int q = 0; q < 4; ++q)
            zb[(mt * 16 + (lane >> 4) * 4 + q) * ZPITCH + nt * 16 + lm] += acc[mt][nt][q];
    }
    __syncthreads();

    // ---- pointwise gates + cell update (2 hidden units / thread) ----
    {
      float hh2[2];
      float cc[2] = {c_a, c_b};
#pragma unroll
      for (int u = 0; u < 2; ++u) {
        const int jn = pj + u;
        float zg[4];
#pragma unroll
        for (int g4 = 0; g4 < 4; ++g4) {
          const int n = g4 * 8 + jn;
          float z = zbuf[ps * ZPITCH + n] + zbuf[64 * ZPITCH + ps * ZPITCH + n];
          z += phB ? b1s[n] : (xs * wi0s[n] + b0s[n]);
          zg[g4] = z;
        }
        const float gi = sigm(zg[0]);
        const float gf = sigm(zg[1]);
        const float gg = tanhx(zg[2]);
        const float go = sigm(zg[3]);
        const float c  = gf * cc[u] + gi * gg;
        cc[u]  = c;
        hh2[u] = go * tanhx(c);
      }
      c_a = cc[0]; c_b = cc[1];
      const unsigned int packed =
          (unsigned int)f2bf(hh2[0]) | ((unsigned int)f2bf(hh2[1]) << 16);
      llc_store4(hbuf + (p & 1) * (BB * HH) + ps * HH + colbase + pj, packed);
      if (!phB) {
        llc_store4(stash + (size_t)ps * 2097152 + (size_t)t * 2048 + 1024 + colbase + pj, packed);
      } else {
        hp2a = hh2[0]; hp2b = hh2[1];
        if (t == 1023) { hl_a = hh2[0]; hl_b = hh2[1]; }
      }
    }

    // ---- publish: syncthreads' vmcnt(0) drains the LLC-direct stores, then
    // owner-only relaxed arrival store; block 0 wave 0 aggregates and sets flag ----
    __syncthreads();
    if (tid == 0)
      __hip_atomic_store(&prog[blockIdx.x << 5], p + 1, __ATOMIC_RELAXED,
                         __HIP_MEMORY_SCOPE_AGENT);
    if (blockIdx.x == 0 && wv == 0 && p < 2047) {
      int* a0 = prog + (lane << 5);
      int* a1 = prog + ((lane + 64) << 5);
      for (;;) {
        const int v0 = __hip_atomic_load(a0, __ATOMIC_RELAXED, __HIP_MEMORY_SCOPE_AGENT);
        const int v1 = __hip_atomic_load(a1, __ATOMIC_RELAXED, __HIP_MEMORY_SCOPE_AGENT);
        if (__all((v0 > p) && (v1 > p))) break;
        __builtin_amdgcn_s_sleep(1);
      }
      if (tid == 0)
        __hip_atomic_store(&flag[p << 2], 1, __ATOMIC_RELAXED, __HIP_MEMORY_SCOPE_AGENT);
    }
  }

  // epilogue: flush h2[1023], final c1 and h1 (plain stores; end-of-kernel
  // completion fence writes back L2 for the host). Safe vs others' stash[1023]
  // prefetch: reaching here implies flag[2046] passed => those loads drained.
  {
    float* o = h2out + (size_t)ps * (TT * HH) + (size_t)1023 * HH + colbase + pj;
    o[0] = hp2a; o[1] = hp2b;
    out[ps * HH + colbase + pj]     = c_a;
    out[ps * HH + colbase + pj + 1] = c_b;
    float* ho = out + BB * HH;
    ho[ps * HH + colbase + pj]     = hl_a;
    ho[ps * HH + colbase + pj + 1] = hl_b;
  }
}

extern "C" void kernel_launch(void* const* d_in, const int* in_sizes, int n_in,
                              void* d_out, int out_size, void* d_ws, size_t ws_size,
                              hipStream_t stream) {
  const float* x   = (const float*)d_in[0];
  const float* Wi0 = (const float*)d_in[1];
  const float* Wh0 = (const float*)d_in[2];
  const float* b0  = (const float*)d_in[3];
  const float* Wi1 = (const float*)d_in[4];
  const float* Wh1 = (const float*)d_in[5];
  const float* b1  = (const float*)d_in[6];

  // ws layout: [0,16K) per-block arrival lines (128 x 128B),
  //            [16K,48K) per-step flag lines (2048 x 16B),
  //            [48K,48K+256K) h double-buffer (2 x 64 x 1024 bf16)
  // total 311296 B -- inside the previously-proven 344064 B footprint.
  int* prog = (int*)d_ws;
  int* flag = (int*)((char*)d_ws + 16384);
  unsigned short* hbuf = (unsigned short*)((char*)d_ws + 49152);

  (void)hipMemsetAsync(d_ws, 0, 49152 + 2 * BB * HH * 2, stream);

  (void)hipFuncSetAttribute((const void*)lstm_persist,
                            hipFuncAttributeMaxDynamicSharedMemorySize, SMEM_BYTES);

  lstm_persist<<<dim3(NBLK), dim3(NTHR), SMEM_BYTES, stream>>>(
      x, Wi0, Wh0, b0, Wi1, Wh1, b1, (float*)d_out, prog, flag, hbuf);
}

// Round 4
// 21007.315 us; speedup vs baseline: 1.4943x; 1.4315x over previous
//
#include <hip/hip_runtime.h>
#include <hip/hip_bf16.h>

#define NBLK 128
#define NTHR 256
#define HH   1024
#define BB   64
#define TT   1024
#define SS   8                 // hidden units per block
#define COLS 32                // 4 gates * SS
#define PITCH 1032             // LDS weight pitch (shorts): pad breaks conflicts, keeps 16B align
#define WELEMS (COLS * PITCH)
#define ZPITCH 33
#define SMEM_BYTES (WELEMS * 2 + 2 * 64 * ZPITCH * 4 + 3 * 32 * 4)  // 83328

typedef __bf16 bf16x8 __attribute__((ext_vector_type(8)));
typedef float  f32x4  __attribute__((ext_vector_type(4)));

__device__ __forceinline__ unsigned short f2bf(float x) {
  unsigned int u = __builtin_bit_cast(unsigned int, x);
  u = (u + 0x7fffu + ((u >> 16) & 1u)) >> 16;   // RNE
  return (unsigned short)u;
}
__device__ __forceinline__ float sigm(float x)  { return 1.f / (1.f + __expf(-x)); }
__device__ __forceinline__ float tanhx(float x) { return 2.f / (1.f + __expf(-2.f * x)) - 1.f; }

// LLC-direct accessors: agent-scope RELAXED atomics -> sc0/sc1 accesses that
// read/write through to the Infinity Cache. All cross-block data uses these, so
// no release/acquire cache maintenance (buffer_wbl2/buffer_inv) is needed:
// __syncthreads' vmcnt(0) drains stores to the LLC before the arrival store, and
// the LLC is the single coherence point.
__device__ __forceinline__ bf16x8 llc_load16(const unsigned short* ptr) {
  struct alignas(16) Q { unsigned long long a, b; } q;
  unsigned long long* pp = (unsigned long long*)ptr;
  q.a = __hip_atomic_load(pp,     __ATOMIC_RELAXED, __HIP_MEMORY_SCOPE_AGENT);
  q.b = __hip_atomic_load(pp + 1, __ATOMIC_RELAXED, __HIP_MEMORY_SCOPE_AGENT);
  return __builtin_bit_cast(bf16x8, q);
}
__device__ __forceinline__ void llc_store4(unsigned short* ptr, unsigned int v) {
  __hip_atomic_store((unsigned int*)ptr, v, __ATOMIC_RELAXED, __HIP_MEMORY_SCOPE_AGENT);
}

// Gather one (1024 x 32) column-slice of a (1024 x 4096) fp32 weight into LDS as bf16.
__device__ __forceinline__ void gather_w(const float* __restrict__ Wg, int colbase,
                                         unsigned short* dst) {
  const int tid = threadIdx.x;
  const int n   = tid & 31;
  const int kg  = tid >> 5;  // 0..7
  const int col = (n >> 3) * HH + colbase + (n & 7);
#pragma unroll 8
  for (int kk = 0; kk < 128; ++kk) {
    const int k = kg * 128 + kk;
    dst[n * PITCH + k] = f2bf(Wg[(size_t)k * 4096 + col]);
  }
}

// Wait for step pm1's flag: single reader on a single read-only line, then
// block-wide broadcast via syncthreads (also the compiler/memory barrier).
__device__ __forceinline__ void wait_flag(int* flag, int pm1) {
  if (threadIdx.x == 0) {
    while (__hip_atomic_load(&flag[pm1 << 2], __ATOMIC_RELAXED,
                             __HIP_MEMORY_SCOPE_AGENT) == 0)
      __builtin_amdgcn_s_sleep(1);
  }
  __syncthreads();
}

// hbuf layout (fragment-linear, per 128KB buffer):
//   [kc 0..31][mt 0..3][l 0..63][8 shorts]
// Consumer: wave wv, A-frag af[mt] for local kc' -> 16B at
//   ((wv*8+kc')*2048 + mt*512 + lane*8) shorts  -- 64 lanes fully coalesced.
// Producer thread (ps, pj) of block bx stores its packed 2 units at
//   kc=bx>>2, mt=ps>>4, l=(ps&15)|((bx&3)<<4), slot=pj
// -> every 128B line written whole by a single block (no partial-line merges).

__global__ void __launch_bounds__(NTHR, 1) lstm_persist(
    const float* __restrict__ x,   const float* __restrict__ Wi0,
    const float* __restrict__ Wh0, const float* __restrict__ b0,
    const float* __restrict__ Wi1, const float* __restrict__ Wh1,
    const float* __restrict__ b1,  float* out,
    int* prog, int* flag, unsigned short* hbuf) {
  extern __shared__ unsigned short smem_us[];
  unsigned short* w0 = smem_us;                 // transient weight staging
  float* zbuf = (float*)(smem_us + WELEMS);     // [2][64][ZPITCH]
  float* wi0s = zbuf + 2 * 64 * ZPITCH;
  float* b0s  = wi0s + 32;
  float* b1s  = b0s + 32;

  const int tid     = threadIdx.x;
  const int lane    = tid & 63;
  const int wv      = tid >> 6;
  const int colbase = blockIdx.x * SS;

  if (tid < 32) {
    const int col = (tid >> 3) * HH + colbase + (tid & 7);
    wi0s[tid] = Wi0[col];
    b0s[tid]  = b0[col];
    b1s[tid]  = b1[col];
  }

  const int kq = wv * 256;
  const int lm = lane & 15;
  const int lk = (lane >> 4) * 8;
  const f32x4 fzero = {0.f, 0.f, 0.f, 0.f};

  // ---- register-resident B fragments (loop-invariant weights) ----
  bf16x8 bW0[16];   // phase A: Wh0; phase B: Wi1   [kc*2+nt]
  bf16x8 bW1[16];   // phase B: Wh1
  gather_w(Wh0, colbase, w0);
  __syncthreads();
#pragma unroll
  for (int kc = 0; kc < 8; ++kc)
#pragma unroll
    for (int nt = 0; nt < 2; ++nt)
      bW0[kc * 2 + nt] =
          *reinterpret_cast<const bf16x8*>(w0 + (nt * 16 + lm) * PITCH + kq + kc * 32 + lk);

  // pointwise ownership: thread -> (sample ps, hidden pair pj, pj+1)
  const int ps = tid >> 2;
  const int pj = (tid & 3) * 2;
  // producer's fragment-linear hbuf slot (shorts offset within a buffer)
  const int hslot = (int)(blockIdx.x >> 2) * 2048 + (ps >> 4) * 512 +
                    (((ps & 15) | ((blockIdx.x & 3) << 4)) << 3) + pj;
  float c_a = 0.f, c_b = 0.f;
  float hl_a = 0.f, hl_b = 0.f;

  float* h2out = out + 2 * BB * HH;
  unsigned short* stash = (unsigned short*)h2out;  // bf16 h1-history in upper-half fp32 slots

  bf16x8 pf[32];   // phase B: prefetched Wi1 A-operand (stash[t]) [kc*4+mt]

  for (int p = 0; p < 2048; ++p) {
    const bool phB = (p >= 1024);
    const int  t   = phB ? (p - 1024) : p;
    const unsigned short* hprev = hbuf + ((p + 1) & 1) * 65536;

    if (p == 1024) {  // phase switch (uniform): stage layer-1 weights into registers
      __syncthreads();
      gather_w(Wi1, colbase, w0);
      __syncthreads();
#pragma unroll
      for (int kc = 0; kc < 8; ++kc)
#pragma unroll
        for (int nt = 0; nt < 2; ++nt)
          bW0[kc * 2 + nt] =
              *reinterpret_cast<const bf16x8*>(w0 + (nt * 16 + lm) * PITCH + kq + kc * 32 + lk);
      __syncthreads();
      gather_w(Wh1, colbase, w0);
      __syncthreads();
#pragma unroll
      for (int kc = 0; kc < 8; ++kc)
#pragma unroll
        for (int nt = 0; nt < 2; ++nt)
          bW1[kc * 2 + nt] =
              *reinterpret_cast<const bf16x8*>(w0 + (nt * 16 + lm) * PITCH + kq + kc * 32 + lk);
      // prefetch stash[0] (written at p=0; drained into LLC ages ago)
      const unsigned short* sb = stash + 1024;
#pragma unroll
      for (int kc = 0; kc < 8; ++kc) {
        const int k0 = kq + kc * 32 + lk;
#pragma unroll
        for (int mt = 0; mt < 4; ++mt)
          pf[kc * 4 + mt] = llc_load16(sb + (size_t)(mt * 16 + lm) * 2097152 + k0);
      }
    }

    f32x4 acc[4][2];
#pragma unroll
    for (int i = 0; i < 4; ++i)
#pragma unroll
      for (int j = 0; j < 2; ++j) acc[i][j] = fzero;

    float xs = 0.f;

    if (!phB) {
      // preload x pre-wait (read-only, L2-resident)
      xs = x[(size_t)ps * TT + t];
      if (p > 0) wait_flag(flag, p - 1);
      // ---- phase A: h_prev @ Wh0 — coalesced fragment-linear loads ----
#pragma unroll
      for (int kc = 0; kc < 8; ++kc) {
        const unsigned short* hb = hprev + (size_t)(wv * 8 + kc) * 2048 + lane * 8;
        bf16x8 af[4];
#pragma unroll
        for (int mt = 0; mt < 4; ++mt)
          af[mt] = llc_load16(hb + mt * 512);
#pragma unroll
        for (int nt = 0; nt < 2; ++nt)
#pragma unroll
          for (int mt = 0; mt < 4; ++mt)
            acc[mt][nt] =
                __builtin_amdgcn_mfma_f32_16x16x32_bf16(af[mt], bW0[kc * 2 + nt], acc[mt][nt], 0, 0, 0);
      }
    } else {
      // ---- phase B matmul 1: h1_hist[t] @ Wi1 — register-only, overlaps the wait ----
#pragma unroll
      for (int kc = 0; kc < 8; ++kc)
#pragma unroll
        for (int nt = 0; nt < 2; ++nt)
#pragma unroll
          for (int mt = 0; mt < 4; ++mt)
            acc[mt][nt] =
                __builtin_amdgcn_mfma_f32_16x16x32_bf16(pf[kc * 4 + mt], bW0[kc * 2 + nt],
                                                        acc[mt][nt], 0, 0, 0);
      wait_flag(flag, p - 1);
      // ---- phase B matmul 2: h_prev @ Wh1 — coalesced fragment-linear loads ----
#pragma unroll
      for (int kc = 0; kc < 8; ++kc) {
        const unsigned short* hb = hprev + (size_t)(wv * 8 + kc) * 2048 + lane * 8;
        bf16x8 af[4];
#pragma unroll
        for (int mt = 0; mt < 4; ++mt)
          af[mt] = llc_load16(hb + mt * 512);
#pragma unroll
        for (int nt = 0; nt < 2; ++nt)
#pragma unroll
          for (int mt = 0; mt < 4; ++mt)
            acc[mt][nt] =
                __builtin_amdgcn_mfma_f32_16x16x32_bf16(af[mt], bW1[kc * 2 + nt], acc[mt][nt], 0, 0, 0);
      }
      // ---- prefetch stash[t+1] for next period (latency hidden across the step) ----
      if (t < 1023) {
        const unsigned short* sb = stash + (size_t)(t + 1) * 2048 + 1024;
#pragma unroll
        for (int kc = 0; kc < 8; ++kc) {
          const int k0 = kq + kc * 32 + lk;
#pragma unroll
          for (int mt = 0; mt < 4; ++mt)
            pf[kc * 4 + mt] = llc_load16(sb + (size_t)(mt * 16 + lm) * 2097152 + k0);
        }
      }
    }

    // ---- K-partial reduction through LDS: buf0 = wv0+wv2, buf1 = wv1+wv3 ----
    if (wv >= 2) {
      float* zb = zbuf + (size_t)(wv - 2) * (64 * ZPITCH);
#pragma unroll
      for (int mt = 0; mt < 4; ++mt)
#pragma unroll
        for (int nt = 0; nt < 2; ++nt)
#pragma unroll
          for (int q = 0; q < 4; ++q)
            zb[(mt * 16 + (lane >> 4) * 4 + q) * ZPITCH + nt * 16 + lm] = acc[mt][nt][q];
    }
    __syncthreads();
    if (wv < 2) {
      float* zb = zbuf + (size_t)wv * (64 * ZPITCH);
#pragma unroll
      for (int mt = 0; mt < 4; ++mt)
#pragma unroll
        for (int nt = 0; nt < 2; ++nt)
#pragma unroll
          for (int q = 0; q < 4; ++q)
            zb[(mt * 16 + (lane >> 4) * 4 + q) * ZPITCH + nt * 16 + lm] += acc[mt][nt][q];
    }
    __syncthreads();

    // ---- pointwise gates + cell update (2 hidden units / thread) ----
    unsigned int packed;
    float h2a = 0.f, h2b = 0.f;
    {
      float hh2[2];
      float cc[2] = {c_a, c_b};
#pragma unroll
      for (int u = 0; u < 2; ++u) {
        const int jn = pj + u;
        float zg[4];
#pragma unroll
        for (int g4 = 0; g4 < 4; ++g4) {
          const int n = g4 * 8 + jn;
          float z = zbuf[ps * ZPITCH + n] + zbuf[64 * ZPITCH + ps * ZPITCH + n];
          z += phB ? b1s[n] : (xs * wi0s[n] + b0s[n]);
          zg[g4] = z;
        }
        const float gi = sigm(zg[0]);
        const float gf = sigm(zg[1]);
        const float gg = tanhx(zg[2]);
        const float go = sigm(zg[3]);
        const float c  = gf * cc[u] + gi * gg;
        cc[u]  = c;
        hh2[u] = go * tanhx(c);
      }
      c_a = cc[0]; c_b = cc[1];
      packed = (unsigned int)f2bf(hh2[0]) | ((unsigned int)f2bf(hh2[1]) << 16);
      // h store pre-publish: fragment-linear slot, full-line coalesced, LLC-resident
      llc_store4(hbuf + (p & 1) * 65536 + hslot, packed);
      if (phB) {
        h2a = hh2[0]; h2b = hh2[1];
        if (t == 1023) { hl_a = hh2[0]; hl_b = hh2[1]; }
      }
    }

    // ---- publish: syncthreads drains the hbuf store (only!), then arrival ----
    __syncthreads();
    if (tid == 0)
      __hip_atomic_store(&prog[blockIdx.x << 5], p + 1, __ATOMIC_RELAXED,
                         __HIP_MEMORY_SCOPE_AGENT);

    // ---- streaming stores POST-publish: fill-from-HBM latency drains during the
    // next step's flag wait instead of gating this step's publish.
    // WAR safety: stash[t]'s last grid-wide read is the prefetch at step 1023+t,
    // drained by publish(1023+t); we observed flag[p-1] (p = 1024+t) before writing.
    if (!phB) {
      llc_store4(stash + (size_t)ps * 2097152 + (size_t)t * 2048 + 1024 + colbase + pj,
                 packed);
    } else {
      float* o = h2out + (size_t)ps * (TT * HH) + (size_t)t * HH + colbase + pj;
      o[0] = h2a; o[1] = h2b;
    }

    // ---- aggregator: block 0 wave 0 collects 128 arrivals, sets the step flag ----
    if (blockIdx.x == 0 && wv == 0 && p < 2047) {
      int* a0 = prog + (lane << 5);
      int* a1 = prog + ((lane + 64) << 5);
      for (;;) {
        const int v0 = __hip_atomic_load(a0, __ATOMIC_RELAXED, __HIP_MEMORY_SCOPE_AGENT);
        const int v1 = __hip_atomic_load(a1, __ATOMIC_RELAXED, __HIP_MEMORY_SCOPE_AGENT);
        if (__all((v0 > p) && (v1 > p))) break;
        __builtin_amdgcn_s_sleep(1);
      }
      if (tid == 0)
        __hip_atomic_store(&flag[p << 2], 1, __ATOMIC_RELAXED, __HIP_MEMORY_SCOPE_AGENT);
    }
  }

  // epilogue: final c1 and h1 (own data; h2[1023] already written post-publish)
  {
    out[ps * HH + colbase + pj]     = c_a;
    out[ps * HH + colbase + pj + 1] = c_b;
    float* ho = out + BB * HH;
    ho[ps * HH + colbase + pj]     = hl_a;
    ho[ps * HH + colbase + pj + 1] = hl_b;
  }
}

extern "C" void kernel_launch(void* const* d_in, const int* in_sizes, int n_in,
                              void* d_out, int out_size, void* d_ws, size_t ws_size,
                              hipStream_t stream) {
  const float* x   = (const float*)d_in[0];
  const float* Wi0 = (const float*)d_in[1];
  const float* Wh0 = (const float*)d_in[2];
  const float* b0  = (const float*)d_in[3];
  const float* Wi1 = (const float*)d_in[4];
  const float* Wh1 = (const float*)d_in[5];
  const float* b1  = (const float*)d_in[6];

  // ws layout: [0,16K) per-block arrival lines (128 x 128B),
  //            [16K,48K) per-step flag lines (2048 x 16B),
  //            [48K,48K+256K) h double-buffer (2 x 65536 shorts, fragment-linear)
  // total 311296 B -- inside the previously-proven footprint.
  int* prog = (int*)d_ws;
  int* flag = (int*)((char*)d_ws + 16384);
  unsigned short* hbuf = (unsigned short*)((char*)d_ws + 49152);

  (void)hipMemsetAsync(d_ws, 0, 49152 + 2 * 65536 * 2, stream);

  (void)hipFuncSetAttribute((const void*)lstm_persist,
                            hipFuncAttributeMaxDynamicSharedMemorySize, SMEM_BYTES);

  lstm_persist<<<dim3(NBLK), dim3(NTHR), SMEM_BYTES, stream>>>(
      x, Wi0, Wh0, b0, Wi1, Wh1, b1, (float*)d_out, prog, flag, hbuf);
}